// Round 2
// baseline (2036.247 us; speedup 1.0000x reference)
//
#include <hip/hip_runtime.h>
#include <stdint.h>

#define N_NODES 50000
#define N_EDGES 1600000

typedef __attribute__((ext_vector_type(8))) short bf16x8;
typedef __attribute__((ext_vector_type(4))) float f32x4;
typedef __attribute__((ext_vector_type(8))) unsigned short u16x8;

__device__ __forceinline__ float b2f(unsigned short u) {
  union { unsigned int i; float f; } v; v.i = ((unsigned int)u) << 16; return v.f;
}
__device__ __forceinline__ unsigned short f2b(float f) {
  union { float f; unsigned int i; } v; v.f = f;
  unsigned int u = v.i;
  u += 0x7fffu + ((u >> 16) & 1u);
  return (unsigned short)(u >> 16);
}

__device__ __forceinline__ void load_lds16(const void* g, void* l) {
  __builtin_amdgcn_global_load_lds(
      (const __attribute__((address_space(1))) unsigned int*)g,
      (__attribute__((address_space(3))) unsigned int*)l, 16, 0, 0);
}

// ---------------- row L2-normalize, fp32 -> bf16 ----------------
__global__ __launch_bounds__(256) void normalize_k(const float* __restrict__ x,
                                                   unsigned short* __restrict__ out) {
  int lane = threadIdx.x & 63;
  int row = blockIdx.x * 4 + (threadIdx.x >> 6);
  const float* p = x + (size_t)row * 512 + lane * 8;
  float4 a = ((const float4*)p)[0];
  float4 b = ((const float4*)p)[1];
  float ss = a.x*a.x + a.y*a.y + a.z*a.z + a.w*a.w
           + b.x*b.x + b.y*b.y + b.z*b.z + b.w*b.w;
#pragma unroll
  for (int off = 1; off < 64; off <<= 1) ss += __shfl_xor(ss, off, 64);
  float s = 1.0f / fmaxf(sqrtf(ss), 1e-12f);
  u16x8 o;
  o[0]=f2b(a.x*s); o[1]=f2b(a.y*s); o[2]=f2b(a.z*s); o[3]=f2b(a.w*s);
  o[4]=f2b(b.x*s); o[5]=f2b(b.y*s); o[6]=f2b(b.z*s); o[7]=f2b(b.w*s);
  *(u16x8*)(out + (size_t)row * 512 + lane * 8) = o;
}

// ---------------- CSR build ----------------
__global__ __launch_bounds__(256) void hist_k(const int* __restrict__ er, int* __restrict__ deg) {
  int i = blockIdx.x * 256 + threadIdx.x;
  if (i < N_EDGES) atomicAdd(&deg[er[i]], 1);
}

__global__ __launch_bounds__(256) void scan1_k(const int* __restrict__ deg, int* __restrict__ out,
                                               int* __restrict__ csum, int n) {
  __shared__ int sd[256];
  int t = threadIdx.x;
  int base = blockIdx.x * 1024;
  int v[4], s = 0;
#pragma unroll
  for (int j = 0; j < 4; ++j) {
    int idx = base + t * 4 + j;
    v[j] = (idx < n) ? deg[idx] : 0;
    s += v[j];
  }
  sd[t] = s;
  __syncthreads();
  for (int off = 1; off < 256; off <<= 1) {
    int xx = (t >= off) ? sd[t - off] : 0;
    __syncthreads();
    sd[t] += xx;
    __syncthreads();
  }
  if (t == 255) csum[blockIdx.x] = sd[255];
  int run = sd[t] - s;
#pragma unroll
  for (int j = 0; j < 4; ++j) {
    int idx = base + t * 4 + j;
    if (idx < n) out[idx] = run;
    run += v[j];
  }
}

__global__ void scan2_k(int* csum, int n) {
  if (threadIdx.x == 0 && blockIdx.x == 0) {
    int s = 0;
    for (int i = 0; i < n; ++i) { int t = csum[i]; csum[i] = s; s += t; }
  }
}

__global__ __launch_bounds__(256) void scan3_k(int* __restrict__ out, const int* __restrict__ csum, int n) {
  int i = blockIdx.x * 256 + threadIdx.x;
  if (i < n) out[i] += csum[i >> 10];
}

__global__ __launch_bounds__(256) void scatter_k(const int* __restrict__ er, const int* __restrict__ ec,
    const float* __restrict__ ev, int* __restrict__ head,
    int* __restrict__ scol, float* __restrict__ sval) {
  int i = blockIdx.x * 256 + threadIdx.x;
  if (i < N_EDGES) {
    int r = er[i];
    int p = atomicAdd(&head[r], 1);
    scol[p] = ec[i];
    sval[p] = ev[i];
  }
}

// ---------------- W [K,N] fp32 -> WT [N,K] bf16 ----------------
__global__ __launch_bounds__(256) void wconv_k(const float* __restrict__ W,
                                               unsigned short* __restrict__ WT, int K, int N) {
  int i = blockIdx.x * 256 + threadIdx.x;
  if (i < N * K) {
    int n = i / K, k = i - n * K;
    WT[i] = f2b(W[(size_t)k * N + n]);
  }
}

// ---------------- CSR SpMM: one wave per row ----------------
// MODE 0: plain, bf16 out. MODE 1: +bias, leaky-relu, bf16 out. MODE 2: +bias, fp32 out.
template <int D, int MODE>
__global__ __launch_bounds__(256) void spmm_k(const unsigned short* __restrict__ in,
    const int* __restrict__ rs, const int* __restrict__ scol, const float* __restrict__ sval,
    const float* __restrict__ bias, void* __restrict__ outv) {
  constexpr int VE = D / 64;  // elements per lane (8 or 16)
  int lane = threadIdx.x & 63;
  int row = blockIdx.x * 4 + (threadIdx.x >> 6);
  int e0 = rs[row];
  int e1 = (row + 1 == N_NODES) ? N_EDGES : rs[row + 1];
  float acc[VE];
#pragma unroll
  for (int j = 0; j < VE; ++j) acc[j] = 0.f;
  const unsigned short* base = in + (size_t)lane * VE;
  for (int e = e0; e < e1; ++e) {
    int c = scol[e];
    float v = sval[e];
    const unsigned short* p = base + (size_t)c * D;
#pragma unroll
    for (int q = 0; q < VE / 8; ++q) {
      u16x8 u = *(const u16x8*)(p + q * 8);
#pragma unroll
      for (int h = 0; h < 8; ++h) acc[q * 8 + h] = fmaf(v, b2f(u[h]), acc[q * 8 + h]);
    }
  }
  size_t obase = (size_t)row * D + lane * VE;
  if (MODE == 2) {
    float* out = (float*)outv;
#pragma unroll
    for (int j = 0; j < VE; ++j) out[obase + j] = acc[j] + bias[lane * VE + j];
  } else {
    unsigned short* out = (unsigned short*)outv;
#pragma unroll
    for (int q = 0; q < VE / 8; ++q) {
      u16x8 o;
#pragma unroll
      for (int h = 0; h < 8; ++h) {
        float xo = acc[q * 8 + h];
        if (MODE == 1) {
          xo += bias[lane * VE + q * 8 + h];
          xo = xo >= 0.f ? xo : 0.2f * xo;
        }
        o[h] = f2b(xo);
      }
      *(u16x8*)(out + obase + q * 8) = o;
    }
  }
}

// ---------------- bf16 MFMA GEMM: C[M,N] = A[M,K] * BT[N,K]^T ----------------
// 128x128 block tile, BK=32, 4 waves 2x2, 64x64 per wave, global_load_lds staging.
// A-rows clamped to M-1 during staging (no padded buffers needed); stores guarded.
template <bool BIAS_RELU>
__global__ __launch_bounds__(256) void gemm_bt_k(
    const unsigned short* __restrict__ A, const unsigned short* __restrict__ BT,
    const float* __restrict__ bias, unsigned short* __restrict__ C,
    int M, int N, int K) {
  __shared__ __align__(16) unsigned short sA[128 * 32];
  __shared__ __align__(16) unsigned short sB[128 * 32];
  int tid = threadIdx.x;
  int lane = tid & 63;
  int wid = tid >> 6;
  int wm = (wid & 1) * 64;
  int wn = (wid >> 1) * 64;
  int mblk = blockIdx.y * 128;
  int nblk = blockIdx.x * 128;
  const unsigned short* Bb = BT + (size_t)nblk * K;
  // staging: chunk c = 16B; row = c>>2, col8 = (c&3)*8 elements. LDS row-major [128][32].
  int c0 = tid, c1 = tid + 256;
  int ar0 = c0 >> 2, ac0 = (c0 & 3) * 8;
  int ar1 = c1 >> 2, ac1 = (c1 & 3) * 8;
  int ra0 = mblk + ar0; if (ra0 > M - 1) ra0 = M - 1;
  int ra1 = mblk + ar1; if (ra1 > M - 1) ra1 = M - 1;
  f32x4 acc[4][4] = {};
  for (int k0 = 0; k0 < K; k0 += 32) {
    load_lds16(A + (size_t)ra0 * K + k0 + ac0, &sA[c0 * 8]);
    load_lds16(A + (size_t)ra1 * K + k0 + ac1, &sA[c1 * 8]);
    load_lds16(Bb + (size_t)ar0 * K + k0 + ac0, &sB[c0 * 8]);
    load_lds16(Bb + (size_t)ar1 * K + k0 + ac1, &sB[c1 * 8]);
    __syncthreads();
    bf16x8 af[4], bfr[4];
    int kq = (lane >> 4) * 8;
    int mr = wm + (lane & 15);
    int nr = wn + (lane & 15);
#pragma unroll
    for (int i = 0; i < 4; ++i) af[i] = *(const bf16x8*)&sA[(mr + i * 16) * 32 + kq];
#pragma unroll
    for (int j = 0; j < 4; ++j) bfr[j] = *(const bf16x8*)&sB[(nr + j * 16) * 32 + kq];
#pragma unroll
    for (int i = 0; i < 4; ++i)
#pragma unroll
      for (int j = 0; j < 4; ++j)
        acc[i][j] = __builtin_amdgcn_mfma_f32_16x16x32_bf16(af[i], bfr[j], acc[i][j], 0, 0, 0);
    __syncthreads();
  }
  // C/D layout: row = (lane>>4)*4 + reg, col = lane&15
  int quad = lane >> 4;
  int lc = lane & 15;
#pragma unroll
  for (int i = 0; i < 4; ++i) {
#pragma unroll
    for (int r = 0; r < 4; ++r) {
      int gm = mblk + wm + i * 16 + quad * 4 + r;
      if (gm < M) {
#pragma unroll
        for (int j = 0; j < 4; ++j) {
          int gn = nblk + wn + j * 16 + lc;
          float v = acc[i][j][r];
          if (BIAS_RELU) { v += bias[gn]; v = v >= 0.f ? v : 0.2f * v; }
          C[(size_t)gm * N + gn] = f2b(v);
        }
      }
    }
  }
}

extern "C" void kernel_launch(void* const* d_in, const int* in_sizes, int n_in,
                              void* d_out, int out_size, void* d_ws, size_t ws_size,
                              hipStream_t stream) {
  (void)in_sizes; (void)n_in; (void)out_size; (void)ws_size;
  const float* x  = (const float*)d_in[0];
  const int* erow = (const int*)d_in[1];
  const int* ecol = (const int*)d_in[2];
  const float* ev = (const float*)d_in[3];
  const float* W0 = (const float*)d_in[4];
  const float* b0 = (const float*)d_in[5];
  const float* W1 = (const float*)d_in[6];
  const float* b1 = (const float*)d_in[7];
  const float* W2 = (const float*)d_in[8];
  const float* b2 = (const float*)d_in[9];

  // ---- workspace layout (total ~174.3 MB) ----
  // pool [0, 153.6M): phase1: norm_out[0,51.2M) | spmm0_out[51.2M,102.4M) | h1chunk[102.4M,153.6M)
  //                   phase2: h2[0,102.4M)      | v[102.4M,153.6M)
  // d_out doubles as scratch: u (bf16 [N,1024] = 102.4MB exactly), overwritten by final fp32 out.
  char* ws = (char*)d_ws;
  unsigned short* norm_out  = (unsigned short*)(ws);
  unsigned short* spmm0_out = (unsigned short*)(ws + 51200000);
  unsigned short* h1chunk   = (unsigned short*)(ws + 102400000);
  unsigned short* h2        = (unsigned short*)(ws);
  unsigned short* vbuf      = (unsigned short*)(ws + 102400000);
  int*   scol = (int*)(ws + 153600000);
  float* sval = (float*)(ws + 160000000);
  int*   rs   = (int*)(ws + 166400000);
  int*   head = (int*)(ws + 166600192);
  int*   deg  = (int*)(ws + 166800384);
  int*   csum = (int*)(ws + 167000576);
  unsigned short* w0t = (unsigned short*)(ws + 167000832);            // 2048x512
  unsigned short* w1t = w0t + (size_t)2048 * 512;                     // 1024x2048
  unsigned short* w2t = w1t + (size_t)1024 * 2048;                    // 512x1024
  unsigned short* u   = (unsigned short*)d_out;                       // [N,1024] bf16

  // ---- CSR build (same work every call) ----
  hipMemsetAsync(deg, 0, N_NODES * 4, stream);
  hist_k<<<6250, 256, 0, stream>>>(erow, deg);
  scan1_k<<<49, 256, 0, stream>>>(deg, rs, csum, N_NODES);
  scan2_k<<<1, 64, 0, stream>>>(csum, 49);
  scan3_k<<<196, 256, 0, stream>>>(rs, csum, N_NODES);
  hipMemcpyAsync(head, rs, N_NODES * 4, hipMemcpyDeviceToDevice, stream);
  scatter_k<<<6250, 256, 0, stream>>>(erow, ecol, ev, head, scol, sval);

  // ---- weights -> transposed bf16 ----
  wconv_k<<<4096, 256, 0, stream>>>(W0, w0t, 512, 2048);
  wconv_k<<<8192, 256, 0, stream>>>(W1, w1t, 2048, 1024);
  wconv_k<<<2048, 256, 0, stream>>>(W2, w2t, 1024, 512);

  // ---- h = normalize(x), bf16 ----
  normalize_k<<<12500, 256, 0, stream>>>(x, norm_out);

  // L0: t = A@h (d=512, spmm-first reassociation)
  spmm_k<512, 0><<<12500, 256, 0, stream>>>(norm_out, rs, scol, sval, nullptr, spmm0_out);

  // L0 GEMM + L1 GEMM, chunked over 4 row-blocks of 12500 so h1 [N,2048] never materializes:
  //   h1_c = lrelu(spmm0_out_c @ W0 + b0); u_c = h1_c @ W1  -> d_out
  for (int c = 0; c < 4; ++c) {
    const unsigned short* a0 = spmm0_out + (size_t)c * 12500 * 512;
    unsigned short* uc = u + (size_t)c * 12500 * 1024;
    gemm_bt_k<true ><<<dim3(16, 98), 256, 0, stream>>>(a0, w0t, b0, h1chunk, 12500, 2048, 512);
    gemm_bt_k<false><<<dim3(8, 98), 256, 0, stream>>>(h1chunk, w1t, nullptr, uc, 12500, 1024, 2048);
  }

  // L1 spmm: h2 = lrelu(A@u + b1)
  spmm_k<1024, 1><<<12500, 256, 0, stream>>>(u, rs, scol, sval, b1, h2);

  // L2: v = h2@W2; out = A@v + b2 (fp32 to d_out, overwrites u which is dead)
  gemm_bt_k<false><<<dim3(4, 391), 256, 0, stream>>>(h2, w2t, nullptr, vbuf, N_NODES, 512, 1024);
  spmm_k<512, 2><<<12500, 256, 0, stream>>>(vbuf, rs, scol, sval, b2, (float*)d_out);
}

// Round 3
// 2034.404 us; speedup vs baseline: 1.0009x; 1.0009x over previous
//
#include <hip/hip_runtime.h>
#include <stdint.h>

#define N_NODES 50000
#define N_EDGES 1600000

typedef __attribute__((ext_vector_type(8))) short bf16x8;
typedef __attribute__((ext_vector_type(4))) float f32x4;
typedef __attribute__((ext_vector_type(8))) unsigned short u16x8;

__device__ __forceinline__ float b2f(unsigned short u) {
  union { unsigned int i; float f; } v; v.i = ((unsigned int)u) << 16; return v.f;
}
__device__ __forceinline__ unsigned short f2b(float f) {
  union { float f; unsigned int i; } v; v.f = f;
  unsigned int u = v.i;
  u += 0x7fffu + ((u >> 16) & 1u);
  return (unsigned short)(u >> 16);
}

__device__ __forceinline__ void load_lds16(const void* g, void* l) {
  __builtin_amdgcn_global_load_lds(
      (const __attribute__((address_space(1))) unsigned int*)g,
      (__attribute__((address_space(3))) unsigned int*)l, 16, 0, 0);
}

// ---------------- row L2-normalize, fp32 -> bf16 ----------------
__global__ __launch_bounds__(256) void normalize_k(const float* __restrict__ x,
                                                   unsigned short* __restrict__ out) {
  int lane = threadIdx.x & 63;
  int row = blockIdx.x * 4 + (threadIdx.x >> 6);
  const float* p = x + (size_t)row * 512 + lane * 8;
  float4 a = ((const float4*)p)[0];
  float4 b = ((const float4*)p)[1];
  float ss = a.x*a.x + a.y*a.y + a.z*a.z + a.w*a.w
           + b.x*b.x + b.y*b.y + b.z*b.z + b.w*b.w;
#pragma unroll
  for (int off = 1; off < 64; off <<= 1) ss += __shfl_xor(ss, off, 64);
  float s = 1.0f / fmaxf(sqrtf(ss), 1e-12f);
  u16x8 o;
  o[0]=f2b(a.x*s); o[1]=f2b(a.y*s); o[2]=f2b(a.z*s); o[3]=f2b(a.w*s);
  o[4]=f2b(b.x*s); o[5]=f2b(b.y*s); o[6]=f2b(b.z*s); o[7]=f2b(b.w*s);
  *(u16x8*)(out + (size_t)row * 512 + lane * 8) = o;
}

// ---------------- CSR build ----------------
__global__ __launch_bounds__(256) void hist_k(const int* __restrict__ er, int* __restrict__ deg) {
  int i = blockIdx.x * 256 + threadIdx.x;
  if (i < N_EDGES) atomicAdd(&deg[er[i]], 1);
}

__global__ __launch_bounds__(256) void scan1_k(const int* __restrict__ deg, int* __restrict__ out,
                                               int* __restrict__ csum, int n) {
  __shared__ int sd[256];
  int t = threadIdx.x;
  int base = blockIdx.x * 1024;
  int v[4], s = 0;
#pragma unroll
  for (int j = 0; j < 4; ++j) {
    int idx = base + t * 4 + j;
    v[j] = (idx < n) ? deg[idx] : 0;
    s += v[j];
  }
  sd[t] = s;
  __syncthreads();
  for (int off = 1; off < 256; off <<= 1) {
    int xx = (t >= off) ? sd[t - off] : 0;
    __syncthreads();
    sd[t] += xx;
    __syncthreads();
  }
  if (t == 255) csum[blockIdx.x] = sd[255];
  int run = sd[t] - s;
#pragma unroll
  for (int j = 0; j < 4; ++j) {
    int idx = base + t * 4 + j;
    if (idx < n) out[idx] = run;
    run += v[j];
  }
}

__global__ void scan2_k(int* csum, int n) {
  if (threadIdx.x == 0 && blockIdx.x == 0) {
    int s = 0;
    for (int i = 0; i < n; ++i) { int t = csum[i]; csum[i] = s; s += t; }
  }
}

__global__ __launch_bounds__(256) void scan3_k(int* __restrict__ out, const int* __restrict__ csum, int n) {
  int i = blockIdx.x * 256 + threadIdx.x;
  if (i < n) out[i] += csum[i >> 10];
}

// edges packed as (col, val-bits) pairs -> one 8B load per edge
__global__ __launch_bounds__(256) void scatter_k(const int* __restrict__ er, const int* __restrict__ ec,
    const float* __restrict__ ev, int* __restrict__ head, int2* __restrict__ ep) {
  int i = blockIdx.x * 256 + threadIdx.x;
  if (i < N_EDGES) {
    int r = er[i];
    int p = atomicAdd(&head[r], 1);
    ep[p] = make_int2(ec[i], __float_as_int(ev[i]));
  }
}

// ---------------- W [K,N] fp32 -> WT [N,K] bf16 ----------------
__global__ __launch_bounds__(256) void wconv_k(const float* __restrict__ W,
                                               unsigned short* __restrict__ WT, int K, int N) {
  int i = blockIdx.x * 256 + threadIdx.x;
  if (i < N * K) {
    int n = i / K, k = i - n * K;
    WT[i] = f2b(W[(size_t)k * N + n]);
  }
}

// ---------------- CSR SpMM: one wave per (row, 512-feature slice) ----------------
// Edge loop unrolled x4: four independent 16B/lane gathers in flight per wave (MLP).
// Feature slicing (D>512) groups slices in dispatch order -> halved gather working set.
// MODE 0: plain, bf16 out. MODE 1: +bias+leaky-relu, bf16 out. MODE 2: +bias, fp32 out.
template <int D, int MODE>
__global__ __launch_bounds__(256) void spmm_k(const unsigned short* __restrict__ in,
    const int* __restrict__ rs, const int2* __restrict__ ep,
    const float* __restrict__ bias, void* __restrict__ outv) {
  constexpr int NS = D / 512;
  int lane = threadIdx.x & 63;
  int blk = blockIdx.x;
  int slice = (NS == 1) ? 0 : (blk / 12500);
  int rowg = (NS == 1) ? blk : (blk - slice * 12500);
  int row = rowg * 4 + (threadIdx.x >> 6);
  int e0 = rs[row];
  int e1 = (row + 1 == N_NODES) ? N_EDGES : rs[row + 1];
  float acc[8] = {0.f, 0.f, 0.f, 0.f, 0.f, 0.f, 0.f, 0.f};
  const unsigned short* base = in + (size_t)slice * 512 + (size_t)lane * 8;
  int e = e0;
  for (; e + 4 <= e1; e += 4) {
    int2 p0 = ep[e];
    int2 p1 = ep[e + 1];
    int2 p2 = ep[e + 2];
    int2 p3 = ep[e + 3];
    u16x8 u0 = *(const u16x8*)(base + (size_t)p0.x * D);
    u16x8 u1 = *(const u16x8*)(base + (size_t)p1.x * D);
    u16x8 u2 = *(const u16x8*)(base + (size_t)p2.x * D);
    u16x8 u3 = *(const u16x8*)(base + (size_t)p3.x * D);
    float v0 = __int_as_float(p0.y), v1 = __int_as_float(p1.y);
    float v2 = __int_as_float(p2.y), v3 = __int_as_float(p3.y);
#pragma unroll
    for (int h = 0; h < 8; ++h) acc[h] = fmaf(v0, b2f(u0[h]), acc[h]);
#pragma unroll
    for (int h = 0; h < 8; ++h) acc[h] = fmaf(v1, b2f(u1[h]), acc[h]);
#pragma unroll
    for (int h = 0; h < 8; ++h) acc[h] = fmaf(v2, b2f(u2[h]), acc[h]);
#pragma unroll
    for (int h = 0; h < 8; ++h) acc[h] = fmaf(v3, b2f(u3[h]), acc[h]);
  }
  for (; e < e1; ++e) {
    int2 p = ep[e];
    u16x8 u = *(const u16x8*)(base + (size_t)p.x * D);
    float v = __int_as_float(p.y);
#pragma unroll
    for (int h = 0; h < 8; ++h) acc[h] = fmaf(v, b2f(u[h]), acc[h]);
  }
  size_t obase = (size_t)row * D + (size_t)slice * 512 + lane * 8;
  int bbase = slice * 512 + lane * 8;
  if (MODE == 2) {
    float* out = (float*)outv;
#pragma unroll
    for (int j = 0; j < 8; ++j) out[obase + j] = acc[j] + bias[bbase + j];
  } else {
    unsigned short* out = (unsigned short*)outv;
    u16x8 o;
#pragma unroll
    for (int h = 0; h < 8; ++h) {
      float xo = acc[h];
      if (MODE == 1) {
        xo += bias[bbase + h];
        xo = xo >= 0.f ? xo : 0.2f * xo;
      }
      o[h] = f2b(xo);
    }
    *(u16x8*)(out + obase) = o;
  }
}

// ---------------- bf16 MFMA GEMM: C[M,N] = A[M,K] * BT[N,K]^T ----------------
// 128x128 block tile, BK=32, 4 waves 2x2, 64x64 per wave, global_load_lds staging.
// A-rows clamped to M-1 during staging (no padded buffers needed); stores guarded.
template <bool BIAS_RELU>
__global__ __launch_bounds__(256) void gemm_bt_k(
    const unsigned short* __restrict__ A, const unsigned short* __restrict__ BT,
    const float* __restrict__ bias, unsigned short* __restrict__ C,
    int M, int N, int K) {
  __shared__ __align__(16) unsigned short sA[128 * 32];
  __shared__ __align__(16) unsigned short sB[128 * 32];
  int tid = threadIdx.x;
  int lane = tid & 63;
  int wid = tid >> 6;
  int wm = (wid & 1) * 64;
  int wn = (wid >> 1) * 64;
  int mblk = blockIdx.y * 128;
  int nblk = blockIdx.x * 128;
  const unsigned short* Bb = BT + (size_t)nblk * K;
  int c0 = tid, c1 = tid + 256;
  int ar0 = c0 >> 2, ac0 = (c0 & 3) * 8;
  int ar1 = c1 >> 2, ac1 = (c1 & 3) * 8;
  int ra0 = mblk + ar0; if (ra0 > M - 1) ra0 = M - 1;
  int ra1 = mblk + ar1; if (ra1 > M - 1) ra1 = M - 1;
  f32x4 acc[4][4] = {};
  for (int k0 = 0; k0 < K; k0 += 32) {
    load_lds16(A + (size_t)ra0 * K + k0 + ac0, &sA[c0 * 8]);
    load_lds16(A + (size_t)ra1 * K + k0 + ac1, &sA[c1 * 8]);
    load_lds16(Bb + (size_t)ar0 * K + k0 + ac0, &sB[c0 * 8]);
    load_lds16(Bb + (size_t)ar1 * K + k0 + ac1, &sB[c1 * 8]);
    __syncthreads();
    bf16x8 af[4], bfr[4];
    int kq = (lane >> 4) * 8;
    int mr = wm + (lane & 15);
    int nr = wn + (lane & 15);
#pragma unroll
    for (int i = 0; i < 4; ++i) af[i] = *(const bf16x8*)&sA[(mr + i * 16) * 32 + kq];
#pragma unroll
    for (int j = 0; j < 4; ++j) bfr[j] = *(const bf16x8*)&sB[(nr + j * 16) * 32 + kq];
#pragma unroll
    for (int i = 0; i < 4; ++i)
#pragma unroll
      for (int j = 0; j < 4; ++j)
        acc[i][j] = __builtin_amdgcn_mfma_f32_16x16x32_bf16(af[i], bfr[j], acc[i][j], 0, 0, 0);
    __syncthreads();
  }
  int quad = lane >> 4;
  int lc = lane & 15;
#pragma unroll
  for (int i = 0; i < 4; ++i) {
#pragma unroll
    for (int r = 0; r < 4; ++r) {
      int gm = mblk + wm + i * 16 + quad * 4 + r;
      if (gm < M) {
#pragma unroll
        for (int j = 0; j < 4; ++j) {
          int gn = nblk + wn + j * 16 + lc;
          float v = acc[i][j][r];
          if (BIAS_RELU) { v += bias[gn]; v = v >= 0.f ? v : 0.2f * v; }
          C[(size_t)gm * N + gn] = f2b(v);
        }
      }
    }
  }
}

extern "C" void kernel_launch(void* const* d_in, const int* in_sizes, int n_in,
                              void* d_out, int out_size, void* d_ws, size_t ws_size,
                              hipStream_t stream) {
  (void)in_sizes; (void)n_in; (void)out_size; (void)ws_size;
  const float* x  = (const float*)d_in[0];
  const int* erow = (const int*)d_in[1];
  const int* ecol = (const int*)d_in[2];
  const float* ev = (const float*)d_in[3];
  const float* W0 = (const float*)d_in[4];
  const float* b0 = (const float*)d_in[5];
  const float* W1 = (const float*)d_in[6];
  const float* b1 = (const float*)d_in[7];
  const float* W2 = (const float*)d_in[8];
  const float* b2 = (const float*)d_in[9];

  // ---- workspace layout (~174.3 MB) ----
  char* ws = (char*)d_ws;
  unsigned short* norm_out  = (unsigned short*)(ws);
  unsigned short* spmm0_out = (unsigned short*)(ws + 51200000);
  unsigned short* h1chunk   = (unsigned short*)(ws + 102400000);
  unsigned short* h2        = (unsigned short*)(ws);
  unsigned short* vbuf      = (unsigned short*)(ws + 102400000);
  int2*  ep   = (int2*)(ws + 153600000);            // 12.8 MB packed (col,val)
  int*   rs   = (int*)(ws + 166400000);
  int*   head = (int*)(ws + 166600192);
  int*   deg  = (int*)(ws + 166800384);
  int*   csum = (int*)(ws + 167000576);
  unsigned short* w0t = (unsigned short*)(ws + 167000832);            // 2048x512
  unsigned short* w1t = w0t + (size_t)2048 * 512;                     // 1024x2048
  unsigned short* w2t = w1t + (size_t)1024 * 2048;                    // 512x1024
  unsigned short* u   = (unsigned short*)d_out;                       // [N,1024] bf16

  // ---- CSR build ----
  hipMemsetAsync(deg, 0, N_NODES * 4, stream);
  hist_k<<<6250, 256, 0, stream>>>(erow, deg);
  scan1_k<<<49, 256, 0, stream>>>(deg, rs, csum, N_NODES);
  scan2_k<<<1, 64, 0, stream>>>(csum, 49);
  scan3_k<<<196, 256, 0, stream>>>(rs, csum, N_NODES);
  hipMemcpyAsync(head, rs, N_NODES * 4, hipMemcpyDeviceToDevice, stream);
  scatter_k<<<6250, 256, 0, stream>>>(erow, ecol, ev, head, ep);

  // ---- weights -> transposed bf16 ----
  wconv_k<<<4096, 256, 0, stream>>>(W0, w0t, 512, 2048);
  wconv_k<<<8192, 256, 0, stream>>>(W1, w1t, 2048, 1024);
  wconv_k<<<2048, 256, 0, stream>>>(W2, w2t, 1024, 512);

  // ---- h = normalize(x), bf16 ----
  normalize_k<<<12500, 256, 0, stream>>>(x, norm_out);

  // L0: t = A@h (d=512, spmm-first reassociation)
  spmm_k<512, 0><<<12500, 256, 0, stream>>>(norm_out, rs, ep, nullptr, spmm0_out);

  // L0 GEMM + L1 GEMM, chunked over 4 row-blocks of 12500 (h1 never materializes)
  for (int c = 0; c < 4; ++c) {
    const unsigned short* a0 = spmm0_out + (size_t)c * 12500 * 512;
    unsigned short* uc = u + (size_t)c * 12500 * 1024;
    gemm_bt_k<true ><<<dim3(16, 98), 256, 0, stream>>>(a0, w0t, b0, h1chunk, 12500, 2048, 512);
    gemm_bt_k<false><<<dim3(8, 98), 256, 0, stream>>>(h1chunk, w1t, nullptr, uc, 12500, 1024, 2048);
  }

  // L1 spmm: h2 = lrelu(A@u + b1)  (2 feature slices)
  spmm_k<1024, 1><<<25000, 256, 0, stream>>>(u, rs, ep, b1, h2);

  // L2: v = h2@W2; out = A@v + b2 (fp32 to d_out, overwrites dead u)
  gemm_bt_k<false><<<dim3(4, 391), 256, 0, stream>>>(h2, w2t, nullptr, vbuf, N_NODES, 512, 1024);
  spmm_k<512, 2><<<12500, 256, 0, stream>>>(vbuf, rs, ep, b2, (float*)d_out);
}

// Round 5
// 1849.694 us; speedup vs baseline: 1.1009x; 1.0999x over previous
//
#include <hip/hip_runtime.h>
#include <stdint.h>

#define N_NODES 50000
#define N_EDGES 1600000
#define NCB 13  // col blocks of 4096: 50000 -> 13

typedef __attribute__((ext_vector_type(8))) short bf16x8;
typedef __attribute__((ext_vector_type(4))) float f32x4;
typedef __attribute__((ext_vector_type(8))) unsigned short u16x8;

__device__ __forceinline__ float b2f(unsigned short u) {
  union { unsigned int i; float f; } v; v.i = ((unsigned int)u) << 16; return v.f;
}
__device__ __forceinline__ unsigned short f2b(float f) {
  union { float f; unsigned int i; } v; v.f = f;
  unsigned int u = v.i;
  u += 0x7fffu + ((u >> 16) & 1u);
  return (unsigned short)(u >> 16);
}

__device__ __forceinline__ void load_lds16(const void* g, void* l) {
  __builtin_amdgcn_global_load_lds(
      (const __attribute__((address_space(1))) unsigned int*)g,
      (__attribute__((address_space(3))) unsigned int*)l, 16, 0, 0);
}

// ---------------- row L2-normalize, fp32 -> bf16 ----------------
__global__ __launch_bounds__(256) void normalize_k(const float* __restrict__ x,
                                                   unsigned short* __restrict__ out) {
  int lane = threadIdx.x & 63;
  int row = blockIdx.x * 4 + (threadIdx.x >> 6);
  const float* p = x + (size_t)row * 512 + lane * 8;
  float4 a = ((const float4*)p)[0];
  float4 b = ((const float4*)p)[1];
  float ss = a.x*a.x + a.y*a.y + a.z*a.z + a.w*a.w
           + b.x*b.x + b.y*b.y + b.z*b.z + b.w*b.w;
#pragma unroll
  for (int off = 1; off < 64; off <<= 1) ss += __shfl_xor(ss, off, 64);
  float s = 1.0f / fmaxf(sqrtf(ss), 1e-12f);
  u16x8 o;
  o[0]=f2b(a.x*s); o[1]=f2b(a.y*s); o[2]=f2b(a.z*s); o[3]=f2b(a.w*s);
  o[4]=f2b(b.x*s); o[5]=f2b(b.y*s); o[6]=f2b(b.z*s); o[7]=f2b(b.w*s);
  *(u16x8*)(out + (size_t)row * 512 + lane * 8) = o;
}

// ---------------- CSR build, edges ordered by (row, col>>12) ----------------
__global__ __launch_bounds__(256) void hist2_k(const int* __restrict__ er, const int* __restrict__ ec,
                                               int* __restrict__ h2) {
  int i = blockIdx.x * 256 + threadIdx.x;
  if (i < N_EDGES) atomicAdd(&h2[er[i] * NCB + (ec[i] >> 12)], 1);
}

__global__ __launch_bounds__(256) void scan1_k(const int* __restrict__ deg, int* __restrict__ out,
                                               int* __restrict__ csum, int n) {
  __shared__ int sd[256];
  int t = threadIdx.x;
  int base = blockIdx.x * 1024;
  int v[4], s = 0;
#pragma unroll
  for (int j = 0; j < 4; ++j) {
    int idx = base + t * 4 + j;
    v[j] = (idx < n) ? deg[idx] : 0;
    s += v[j];
  }
  sd[t] = s;
  __syncthreads();
  for (int off = 1; off < 256; off <<= 1) {
    int xx = (t >= off) ? sd[t - off] : 0;
    __syncthreads();
    sd[t] += xx;
    __syncthreads();
  }
  if (t == 255) csum[blockIdx.x] = sd[255];
  int run = sd[t] - s;
#pragma unroll
  for (int j = 0; j < 4; ++j) {
    int idx = base + t * 4 + j;
    if (idx < n) out[idx] = run;
    run += v[j];
  }
}

// single-block parallel exclusive scan, n <= 768
__global__ __launch_bounds__(256) void scan2p_k(int* __restrict__ csum, int n) {
  __shared__ int sd[256];
  int t = threadIdx.x;
  int v[3], s = 0;
#pragma unroll
  for (int j = 0; j < 3; ++j) {
    int idx = t * 3 + j;
    v[j] = (idx < n) ? csum[idx] : 0;
    s += v[j];
  }
  sd[t] = s;
  __syncthreads();
  for (int off = 1; off < 256; off <<= 1) {
    int xx = (t >= off) ? sd[t - off] : 0;
    __syncthreads();
    sd[t] += xx;
    __syncthreads();
  }
  int run = sd[t] - s;
#pragma unroll
  for (int j = 0; j < 3; ++j) {
    int idx = t * 3 + j;
    if (idx < n) csum[idx] = run;
    run += v[j];
  }
}

__global__ __launch_bounds__(256) void scan3_k(int* __restrict__ out, const int* __restrict__ csum, int n) {
  int i = blockIdx.x * 256 + threadIdx.x;
  if (i < n) out[i] += csum[i >> 10];
}

__global__ __launch_bounds__(256) void extract_k(const int* __restrict__ rs2, int* __restrict__ rs_s) {
  int i = blockIdx.x * 256 + threadIdx.x;
  if (i < N_NODES) rs_s[i] = rs2[i * NCB];
  if (i == N_NODES) rs_s[i] = N_EDGES;
}

__global__ __launch_bounds__(256) void scatter2_k(const int* __restrict__ er, const int* __restrict__ ec,
    const float* __restrict__ ev, int* __restrict__ head2, int2* __restrict__ ep) {
  int i = blockIdx.x * 256 + threadIdx.x;
  if (i < N_EDGES) {
    int r = er[i], c = ec[i];
    int p = atomicAdd(&head2[r * NCB + (c >> 12)], 1);
    ep[p] = make_int2(c, __float_as_int(ev[i]));
  }
}

// ---------------- W [K,N] fp32 -> WT [N,K] bf16 ----------------
__global__ __launch_bounds__(256) void wconv_k(const float* __restrict__ W,
                                               unsigned short* __restrict__ WT, int K, int N) {
  int i = blockIdx.x * 256 + threadIdx.x;
  if (i < N * K) {
    int n = i / K, k = i - n * K;
    WT[i] = f2b(W[(size_t)k * N + n]);
  }
}

// ---------------- CSR SpMM: one wave per (row, 512-feature slice) ----------------
// Columns defensively clamped to [0, N_NODES) so an indexing bug reads in-bounds
// (absmax failure with counters) instead of faulting on poisoned workspace.
template <int D, int MODE>
__global__ __launch_bounds__(256) void spmm_k(const unsigned short* __restrict__ in,
    const int* __restrict__ rs, const int2* __restrict__ ep,
    const float* __restrict__ bias, void* __restrict__ outv) {
  constexpr int NS = D / 512;
  int lane = threadIdx.x & 63;
  int blk = blockIdx.x;
  int slice = (NS == 1) ? 0 : (blk / 12500);
  int rowg = (NS == 1) ? blk : (blk - slice * 12500);
  int row = rowg * 4 + (threadIdx.x >> 6);
  int e0 = rs[row];
  int e1 = rs[row + 1];
  float acc[8] = {0.f, 0.f, 0.f, 0.f, 0.f, 0.f, 0.f, 0.f};
  const unsigned short* base = in + (size_t)slice * 512 + (size_t)lane * 8;
  int e = e0;
  for (; e + 4 <= e1; e += 4) {
    int2 p0 = ep[e];
    int2 p1 = ep[e + 1];
    int2 p2 = ep[e + 2];
    int2 p3 = ep[e + 3];
    unsigned c0 = (unsigned)p0.x < N_NODES ? (unsigned)p0.x : 0u;
    unsigned c1 = (unsigned)p1.x < N_NODES ? (unsigned)p1.x : 0u;
    unsigned c2 = (unsigned)p2.x < N_NODES ? (unsigned)p2.x : 0u;
    unsigned c3 = (unsigned)p3.x < N_NODES ? (unsigned)p3.x : 0u;
    u16x8 u0 = *(const u16x8*)(base + (size_t)c0 * D);
    u16x8 u1 = *(const u16x8*)(base + (size_t)c1 * D);
    u16x8 u2 = *(const u16x8*)(base + (size_t)c2 * D);
    u16x8 u3 = *(const u16x8*)(base + (size_t)c3 * D);
    float v0 = __int_as_float(p0.y), v1 = __int_as_float(p1.y);
    float v2 = __int_as_float(p2.y), v3 = __int_as_float(p3.y);
#pragma unroll
    for (int h = 0; h < 8; ++h) acc[h] = fmaf(v0, b2f(u0[h]), acc[h]);
#pragma unroll
    for (int h = 0; h < 8; ++h) acc[h] = fmaf(v1, b2f(u1[h]), acc[h]);
#pragma unroll
    for (int h = 0; h < 8; ++h) acc[h] = fmaf(v2, b2f(u2[h]), acc[h]);
#pragma unroll
    for (int h = 0; h < 8; ++h) acc[h] = fmaf(v3, b2f(u3[h]), acc[h]);
  }
  for (; e < e1; ++e) {
    int2 p = ep[e];
    unsigned c = (unsigned)p.x < N_NODES ? (unsigned)p.x : 0u;
    u16x8 u = *(const u16x8*)(base + (size_t)c * D);
    float v = __int_as_float(p.y);
#pragma unroll
    for (int h = 0; h < 8; ++h) acc[h] = fmaf(v, b2f(u[h]), acc[h]);
  }
  size_t obase = (size_t)row * D + (size_t)slice * 512 + lane * 8;
  int bbase = slice * 512 + lane * 8;
  if (MODE == 2) {
    float* out = (float*)outv;
#pragma unroll
    for (int j = 0; j < 8; ++j) out[obase + j] = acc[j] + bias[bbase + j];
  } else {
    unsigned short* out = (unsigned short*)outv;
    u16x8 o;
#pragma unroll
    for (int h = 0; h < 8; ++h) {
      float xo = acc[h];
      if (MODE == 1) {
        xo += bias[bbase + h];
        xo = xo >= 0.f ? xo : 0.2f * xo;
      }
      o[h] = f2b(xo);
    }
    *(u16x8*)(out + obase) = o;
  }
}

// ---------------- bf16 MFMA GEMM: C[M,N] = A[M,K] * BT[N,K]^T ----------------
template <bool BIAS_RELU>
__global__ __launch_bounds__(256) void gemm_bt_k(
    const unsigned short* __restrict__ A, const unsigned short* __restrict__ BT,
    const float* __restrict__ bias, unsigned short* __restrict__ C,
    int M, int N, int K) {
  __shared__ __align__(16) unsigned short sA[128 * 32];
  __shared__ __align__(16) unsigned short sB[128 * 32];
  int tid = threadIdx.x;
  int lane = tid & 63;
  int wid = tid >> 6;
  int wm = (wid & 1) * 64;
  int wn = (wid >> 1) * 64;
  int mblk = blockIdx.y * 128;
  int nblk = blockIdx.x * 128;
  const unsigned short* Bb = BT + (size_t)nblk * K;
  int c0 = tid, c1 = tid + 256;
  int ar0 = c0 >> 2, ac0 = (c0 & 3) * 8;
  int ar1 = c1 >> 2, ac1 = (c1 & 3) * 8;
  int ra0 = mblk + ar0; if (ra0 > M - 1) ra0 = M - 1;
  int ra1 = mblk + ar1; if (ra1 > M - 1) ra1 = M - 1;
  f32x4 acc[4][4] = {};
  for (int k0 = 0; k0 < K; k0 += 32) {
    load_lds16(A + (size_t)ra0 * K + k0 + ac0, &sA[c0 * 8]);
    load_lds16(A + (size_t)ra1 * K + k0 + ac1, &sA[c1 * 8]);
    load_lds16(Bb + (size_t)ar0 * K + k0 + ac0, &sB[c0 * 8]);
    load_lds16(Bb + (size_t)ar1 * K + k0 + ac1, &sB[c1 * 8]);
    __syncthreads();
    bf16x8 af[4], bfr[4];
    int kq = (lane >> 4) * 8;
    int mr = wm + (lane & 15);
    int nr = wn + (lane & 15);
#pragma unroll
    for (int i = 0; i < 4; ++i) af[i] = *(const bf16x8*)&sA[(mr + i * 16) * 32 + kq];
#pragma unroll
    for (int j = 0; j < 4; ++j) bfr[j] = *(const bf16x8*)&sB[(nr + j * 16) * 32 + kq];
#pragma unroll
    for (int i = 0; i < 4; ++i)
#pragma unroll
      for (int j = 0; j < 4; ++j)
        acc[i][j] = __builtin_amdgcn_mfma_f32_16x16x32_bf16(af[i], bfr[j], acc[i][j], 0, 0, 0);
    __syncthreads();
  }
  int quad = lane >> 4;
  int lc = lane & 15;
#pragma unroll
  for (int i = 0; i < 4; ++i) {
#pragma unroll
    for (int r = 0; r < 4; ++r) {
      int gm = mblk + wm + i * 16 + quad * 4 + r;
      if (gm < M) {
#pragma unroll
        for (int j = 0; j < 4; ++j) {
          int gn = nblk + wn + j * 16 + lc;
          float v = acc[i][j][r];
          if (BIAS_RELU) { v += bias[gn]; v = v >= 0.f ? v : 0.2f * v; }
          C[(size_t)gm * N + gn] = f2b(v);
        }
      }
    }
  }
}

extern "C" void kernel_launch(void* const* d_in, const int* in_sizes, int n_in,
                              void* d_out, int out_size, void* d_ws, size_t ws_size,
                              hipStream_t stream) {
  (void)in_sizes; (void)n_in; (void)out_size;
  const float* x  = (const float*)d_in[0];
  const int* erow = (const int*)d_in[1];
  const int* ecol = (const int*)d_in[2];
  const float* ev = (const float*)d_in[3];
  const float* W0 = (const float*)d_in[4];
  const float* b0 = (const float*)d_in[5];
  const float* W1 = (const float*)d_in[6];
  const float* b1 = (const float*)d_in[7];
  const float* W2 = (const float*)d_in[8];
  const float* b2 = (const float*)d_in[9];

  // ---- persistent meta (after the activation pool) ----
  const size_t POOL_T1 = 256000000;   // h1 full (204.8M, norm_out overlaid) + spmm0_out
  const size_t POOL_T2 = 204800000;   // norm + spmm0 + h1 half-chunk
  const size_t POOL_T3 = 153600000;   // norm + spmm0 + h1 quarter-chunk
  const size_t META = 12800000 + 200064 + 7340032;
  int tier = (ws_size >= POOL_T1 + META) ? 1 : (ws_size >= POOL_T2 + META) ? 2 : 3;
  size_t pool_sz = (tier == 1) ? POOL_T1 : (tier == 2) ? POOL_T2 : POOL_T3;

  char* ws = (char*)d_ws;
  int2*  ep   = (int2*)(ws + pool_sz);
  int*   rs_s = (int*)(ws + pool_sz + 12800000);
  unsigned short* w0t = (unsigned short*)(ws + pool_sz + 12800000 + 200064);
  unsigned short* w1t = w0t + (size_t)2048 * 512;
  unsigned short* w2t = w1t + (size_t)1024 * 2048;
  // build-time transients live in the (then-dead) activation pool
  int* rs2   = (int*)(ws);                  // (650000+1)*4
  int* csum  = (int*)(ws + 2600064);        // 4KB
  int* head2 = (int*)(ws + 2604160);        // 2.6MB
  unsigned short* u = (unsigned short*)d_out;  // [N,1024] bf16 scratch

  // ---- CSR build: edges ordered by (row, col>>12) for L2 sweep locality ----
  hipMemsetAsync(rs2, 0, 2600064, stream);
  hist2_k<<<6250, 256, 0, stream>>>(erow, ecol, rs2);
  scan1_k<<<635, 256, 0, stream>>>(rs2, rs2, csum, N_NODES * NCB);
  scan2p_k<<<1, 256, 0, stream>>>(csum, 635);
  scan3_k<<<2540, 256, 0, stream>>>(rs2, csum, N_NODES * NCB);  // 2540*256 >= 650000 (R4 bug: was 635)
  extract_k<<<196, 256, 0, stream>>>(rs2, rs_s);
  hipMemcpyAsync(head2, rs2, (size_t)N_NODES * NCB * 4, hipMemcpyDeviceToDevice, stream);
  scatter2_k<<<6250, 256, 0, stream>>>(erow, ecol, ev, head2, ep);

  // ---- weights -> transposed bf16 ----
  wconv_k<<<4096, 256, 0, stream>>>(W0, w0t, 512, 2048);
  wconv_k<<<8192, 256, 0, stream>>>(W1, w1t, 2048, 1024);
  wconv_k<<<2048, 256, 0, stream>>>(W2, w2t, 1024, 512);

  if (tier == 1) {
    unsigned short* h1        = (unsigned short*)(ws);              // 204.8M
    unsigned short* norm_out  = (unsigned short*)(ws);              // overlays h1 (dead before h1 written)
    unsigned short* spmm0_out = (unsigned short*)(ws + 204800000);  // 51.2M
    unsigned short* h2        = (unsigned short*)(ws);              // overlays h1 (dead)
    unsigned short* vbuf      = (unsigned short*)(ws + 102400000);
    normalize_k<<<12500, 256, 0, stream>>>(x, norm_out);
    spmm_k<512, 0><<<12500, 256, 0, stream>>>(norm_out, rs_s, ep, nullptr, spmm0_out);
    gemm_bt_k<true ><<<dim3(16, 391), 256, 0, stream>>>(spmm0_out, w0t, b0, h1, N_NODES, 2048, 512);
    gemm_bt_k<false><<<dim3(8, 391), 256, 0, stream>>>(h1, w1t, nullptr, u, N_NODES, 1024, 2048);
    spmm_k<1024, 1><<<25000, 256, 0, stream>>>(u, rs_s, ep, b1, h2);
    gemm_bt_k<false><<<dim3(4, 391), 256, 0, stream>>>(h2, w2t, nullptr, vbuf, N_NODES, 512, 1024);
    spmm_k<512, 2><<<12500, 256, 0, stream>>>(vbuf, rs_s, ep, b2, (float*)d_out);
  } else {
    int nchunk = (tier == 2) ? 2 : 4;
    int crows = (tier == 2) ? 25000 : 12500;
    int ytiles = (tier == 2) ? 196 : 98;
    unsigned short* norm_out  = (unsigned short*)(ws);
    unsigned short* spmm0_out = (unsigned short*)(ws + 51200000);
    unsigned short* h1chunk   = (unsigned short*)(ws + 102400000);
    unsigned short* h2        = (unsigned short*)(ws);
    unsigned short* vbuf      = (unsigned short*)(ws + 102400000);
    normalize_k<<<12500, 256, 0, stream>>>(x, norm_out);
    spmm_k<512, 0><<<12500, 256, 0, stream>>>(norm_out, rs_s, ep, nullptr, spmm0_out);
    for (int c = 0; c < nchunk; ++c) {
      const unsigned short* a0 = spmm0_out + (size_t)c * crows * 512;
      unsigned short* uc = u + (size_t)c * crows * 1024;
      gemm_bt_k<true ><<<dim3(16, ytiles), 256, 0, stream>>>(a0, w0t, b0, h1chunk, crows, 2048, 512);
      gemm_bt_k<false><<<dim3(8, ytiles), 256, 0, stream>>>(h1chunk, w1t, nullptr, uc, crows, 1024, 2048);
    }
    spmm_k<1024, 1><<<25000, 256, 0, stream>>>(u, rs_s, ep, b1, h2);
    gemm_bt_k<false><<<dim3(4, 391), 256, 0, stream>>>(h2, w2t, nullptr, vbuf, N_NODES, 512, 1024);
    spmm_k<512, 2><<<12500, 256, 0, stream>>>(vbuf, rs_s, ep, b2, (float*)d_out);
  }
}